// Round 7
// baseline (519.857 us; speedup 1.0000x reference)
//
#include <hip/hip_runtime.h>

#define D 64
#define WIN 2048
#define NTL(p) __builtin_nontemporal_load(p)

// ---------------- bf16 helpers ----------------
__device__ __forceinline__ float blo(unsigned u) { return __uint_as_float(u << 16); }
__device__ __forceinline__ float bhi(unsigned u) { return __uint_as_float(u & 0xffff0000u); }
__device__ __forceinline__ unsigned rne(float f) {
    unsigned u = __float_as_uint(f);
    return (u + 0x7fffu + ((u >> 16) & 1u)) >> 16;
}
__device__ __forceinline__ unsigned packbf(float a, float b) {
    unsigned ub = __float_as_uint(b);
    return rne(a) | ((ub + 0x7fffu + ((ub >> 16) & 1u)) & 0xffff0000u);
}
__device__ __forceinline__ void add4(float4* p, float a, float b, float c, float d) {
    float4 o = *p; o.x += a; o.y += b; o.z += c; o.w += d; *p = o;
}

// ---------------- fused bf16-convert + 3-graph bucket histogram ----------------
// blocks [0,768): histogram (3 graphs x 256 chunks); blocks >=768: bf16 conversion.
__global__ void prep_kernel(const float* __restrict__ u, const float* __restrict__ b,
                            const float* __restrict__ it,
                            unsigned* __restrict__ SU, unsigned* __restrict__ SB,
                            unsigned* __restrict__ SI, int nU2, int nB2, int nI2,
                            const int* __restrict__ r0, const int* __restrict__ r1,
                            const int* __restrict__ r2,
                            int ne0, int ne1, int ne2, int n0, int n1, int n2,
                            int* __restrict__ histG) {
    __shared__ int h[512];
    int t = threadIdx.x;
    if (blockIdx.x < 768) {
        int g = blockIdx.x >> 8, blk = blockIdx.x & 255;
        const int* rows = (g == 0) ? r0 : (g == 1) ? r1 : r2;
        int ne = (g == 0) ? ne0 : (g == 1) ? ne1 : ne2;
        unsigned n = (unsigned)((g == 0) ? n0 : (g == 1) ? n1 : n2);
        h[t] = 0; h[t + 256] = 0;
        __syncthreads();
        int C = (ne + 255) >> 8;
        int e0 = blk * C, e1 = min(ne, e0 + C);
        for (int e = e0 + t; e < e1; e += 256) {
            unsigned bb = ((unsigned)rows[e] << 9) / n;
            atomicAdd(&h[bb], 1);
        }
        __syncthreads();
        histG[(((g << 9) | t) << 8) | blk] = h[t];
        histG[(((g << 9) | (t + 256)) << 8) | blk] = h[t + 256];
    } else {
        int i = (blockIdx.x - 768) * 256 + t;
        if (i < nU2) {
            float2 f = ((const float2*)u)[i];
            SU[i] = packbf(f.x, f.y);
        } else if (i < nU2 + nB2) {
            int j = i - nU2;
            float2 f = ((const float2*)b)[j];
            SB[j] = packbf(f.x, f.y);
        } else if (i < nU2 + nB2 + nI2) {
            int j = i - nU2 - nB2;
            float2 f = ((const float2*)it)[j];
            SI[j] = packbf(f.x, f.y);
        }
    }
}

__global__ void scan1_kernel(const int* __restrict__ deg, int* __restrict__ rs,
                             int* __restrict__ bsum, int n) {
    __shared__ int tmp[256];
    int t = threadIdx.x;
    int g = blockIdx.x * 256 + t;
    int v = (g < n) ? deg[g] : 0;
    tmp[t] = v;
    __syncthreads();
    for (int off = 1; off < 256; off <<= 1) {
        int x = (t >= off) ? tmp[t - off] : 0;
        __syncthreads();
        tmp[t] += x;
        __syncthreads();
    }
    if (g < n) rs[g] = tmp[t] - v;
    if (t == 255) bsum[blockIdx.x] = tmp[255];
}

__global__ void scan2_kernel(int* __restrict__ bsum, int B) {
    __shared__ int tmp[2048];
    int t = threadIdx.x;
    int v0 = (t < B) ? bsum[t] : 0;
    int v1 = (t + 1024 < B) ? bsum[t + 1024] : 0;
    tmp[t] = v0; tmp[t + 1024] = v1;
    __syncthreads();
    for (int off = 1; off < 2048; off <<= 1) {
        int a0 = (t >= off) ? tmp[t - off] : 0;
        int a1 = ((t + 1024) >= off) ? tmp[t + 1024 - off] : 0;
        __syncthreads();
        tmp[t] += a0; tmp[t + 1024] += a1;
        __syncthreads();
    }
    if (t < B) bsum[t] = tmp[t] - v0;
    if (t + 1024 < B) bsum[t + 1024] = tmp[t + 1024] - v1;
}

// scan3 folded into the two consumers below: hofs[i] is exclusive-within-block,
// bsum[i>>8] is the block offset -> absolute = hofs[i] + bsum[i>>8].

// LDS-staged: local hist -> local scan -> scatter into LDS -> per-bucket coalesced copy out.
__global__ void bucket_scatter_kernel(const int* __restrict__ r0, const int* __restrict__ c0,
                                      const int* __restrict__ r1, const int* __restrict__ c1,
                                      const int* __restrict__ r2, const int* __restrict__ c2,
                                      int ne0, int ne1, int ne2, int n0, int n1, int n2,
                                      const int* __restrict__ hofs, const int* __restrict__ bsum,
                                      unsigned* __restrict__ ebuf) {
    __shared__ unsigned se[8192];    // staged packed edges (chunk <= 6250)
    __shared__ int h[512];
    __shared__ int lofs[512];
    __shared__ int cur[512];
    __shared__ int gb[512];
    __shared__ int tmp[512];
    int t = threadIdx.x;
    int g = blockIdx.x >> 8, blk = blockIdx.x & 255;
    const int* rows = (g == 0) ? r0 : (g == 1) ? r1 : r2;
    const int* cols = (g == 0) ? c0 : (g == 1) ? c1 : c2;
    int ne = (g == 0) ? ne0 : (g == 1) ? ne1 : ne2;
    int n  = (g == 0) ? n0  : (g == 1) ? n1  : n2;
    h[t] = 0; h[t + 256] = 0;
    __syncthreads();
    int C = (ne + 255) >> 8;
    int e0 = blk * C, e1 = min(ne, e0 + C);
    for (int e = e0 + t; e < e1; e += 256) {
        unsigned b = ((unsigned)rows[e] << 9) / (unsigned)n;
        atomicAdd(&h[b], 1);
    }
    __syncthreads();
    tmp[t] = h[t]; tmp[t + 256] = h[t + 256];
    __syncthreads();
    for (int off = 1; off < 512; off <<= 1) {
        int a0 = (t >= off) ? tmp[t - off] : 0;
        int a1 = ((t + 256) >= off) ? tmp[t + 256 - off] : 0;
        __syncthreads();
        tmp[t] += a0; tmp[t + 256] += a1;
        __syncthreads();
    }
    lofs[t] = tmp[t] - h[t]; lofs[t + 256] = tmp[t + 256] - h[t + 256];
    cur[t] = lofs[t]; cur[t + 256] = lofs[t + 256];
    gb[t] = hofs[(((g << 9) | t) << 8) | blk] + bsum[(g << 9) | t];
    gb[t + 256] = hofs[(((g << 9) | (t + 256)) << 8) | blk] + bsum[(g << 9) | (t + 256)];
    __syncthreads();
    for (int e = e0 + t; e < e1; e += 256) {
        int r = rows[e];
        unsigned b = ((unsigned)r << 9) / (unsigned)n;
        int rb0v = ((int)b * n + 511) >> 9;
        int p = atomicAdd(&cur[b], 1);
        se[p] = ((unsigned)(r - rb0v) << 23) | (unsigned)cols[e];
    }
    __syncthreads();
    int wid = t >> 6, lane = t & 63;
    for (int b = wid; b < 512; b += 4) {
        int lb = lofs[b], len = cur[b] - lb, gbb = gb[b];
        for (int j = lane; j < len; j += 64) ebuf[gbb + j] = se[lb + j];
    }
}

// LDS-staged: scatter columns into LDS by row-cursor, then sequential ccol write.
__global__ void sort_bucket_kernel(const unsigned* __restrict__ ebuf, const int* __restrict__ hofs,
                                   const int* __restrict__ bsum,
                                   int* __restrict__ rs0, int* __restrict__ rs1, int* __restrict__ rs2,
                                   float* __restrict__ isd0, float* __restrict__ isd1,
                                   float* __restrict__ isd2, int* __restrict__ ccol,
                                   int ne0, int ne1, int ne2, int n0, int n1, int n2) {
    __shared__ int cnt[256];
    __shared__ int pfx[256];
    __shared__ int scol[8192];
    int t = threadIdx.x;
    int g = blockIdx.x >> 9, b = blockIdx.x & 511;
    int ne = (g == 0) ? ne0 : (g == 1) ? ne1 : ne2;
    int n  = (g == 0) ? n0  : (g == 1) ? n1  : n2;
    int O  = (g == 0) ? 0   : (g == 1) ? ne0 : ne0 + ne1;
    int*   rs  = (g == 0) ? rs0  : (g == 1) ? rs1  : rs2;
    float* isd = (g == 0) ? isd0 : (g == 1) ? isd1 : isd2;
    int rb0 = (b * n + 511) >> 9;
    int rb1 = ((b + 1) * n + 511) >> 9;
    int R = rb1 - rb0;
    cnt[t] = 0;
    __syncthreads();
    int base = hofs[((g << 9) | b) << 8] + bsum[(g << 9) | b];
    int end  = (b == 511) ? (O + ne)
                          : hofs[((g << 9) | (b + 1)) << 8] + bsum[(g << 9) | (b + 1)];
    int E = end - base;
    for (int e = base + t; e < end; e += 256)
        atomicAdd(&cnt[ebuf[e] >> 23], 1);
    __syncthreads();
    pfx[t] = cnt[t];
    __syncthreads();
    for (int off = 1; off < 256; off <<= 1) {
        int v = (t >= off) ? pfx[t - off] : 0;
        __syncthreads();
        pfx[t] += v;
        __syncthreads();
    }
    int c0 = cnt[t], ex = pfx[t] - c0;
    if (t < R) {
        rs[rb0 + t] = base + ex - O;
        isd[rb0 + t] = 1.0f / (sqrtf((float)c0) + 1e-8f);
    }
    __syncthreads();
    bool fits = (E <= 8192);
    cnt[t] = fits ? ex : (base + ex);
    __syncthreads();
    for (int e = base + t; e < end; e += 256) {
        unsigned p = ebuf[e];
        int pos = atomicAdd(&cnt[p >> 23], 1);
        if (fits) scol[pos] = (int)(p & 0x7fffffu);
        else      ccol[pos] = (int)(p & 0x7fffffu);
    }
    if (fits) {
        __syncthreads();
        for (int j = t; j < E; j += 256) ccol[base + j] = scol[j];
    }
    if (b == 511 && t == 0) rs[n] = ne;
}

// ---------------- window-local degree sort (WIN=2048, one block/window) ----------------
__device__ __forceinline__ int row_deg(int list, int r, const int* rs_ui, const int* rs_bi,
                                       const int* rs_ub, int n_ui, int NU) {
    const int* rs; int rr;
    if (list == 0) { if (r < n_ui) { rs = rs_ui; rr = r; } else { rs = rs_bi; rr = r - n_ui; } }
    else if (list == 1) { rs = rs_ub; rr = r; }
    else { if (r < NU) { rs = rs_ui; rr = r; } else { rs = rs_bi; rr = r - NU; } }
    return rs[rr + 1] - rs[rr];
}

__global__ void winsort_kernel(const int* __restrict__ rs_ui, const int* __restrict__ rs_bi,
                               const int* __restrict__ rs_ub,
                               int n_ui, int NU, int n0, int n1, int n2,
                               int w0, int w1,
                               int* __restrict__ perm0, int* __restrict__ perm1,
                               int* __restrict__ perm2) {
    __shared__ int hist[256];
    __shared__ int pfx[256];
    int t = threadIdx.x;
    int blk = blockIdx.x, list, wbase, n; int* perm;
    if (blk < w0)           { list = 0; wbase = blk * WIN;             n = n0; perm = perm0; }
    else if (blk < w0 + w1) { list = 1; wbase = (blk - w0) * WIN;      n = n1; perm = perm1; }
    else                    { list = 2; wbase = (blk - w0 - w1) * WIN; n = n2; perm = perm2; }
    hist[t] = 0;
    __syncthreads();
    int lim = min(n - wbase, WIN);
    int bins[8], ranks[8];
#pragma unroll
    for (int i = 0; i < 8; ++i) {
        int rr = i * 256 + t;
        if (rr < lim) {
            int d = row_deg(list, wbase + rr, rs_ui, rs_bi, rs_ub, n_ui, NU);
            int b = 255 - min(d, 255);          // descending: long rows first
            bins[i] = b;
            ranks[i] = atomicAdd(&hist[b], 1);
        } else bins[i] = -1;
    }
    __syncthreads();
    int h = hist[t];
    pfx[t] = h;
    __syncthreads();
    for (int off = 1; off < 256; off <<= 1) {
        int x = (t >= off) ? pfx[t - off] : 0;
        __syncthreads();
        pfx[t] += x;
        __syncthreads();
    }
    hist[t] = pfx[t] - h;                        // exclusive base per bin
    __syncthreads();
#pragma unroll
    for (int i = 0; i < 8; ++i)
        if (bins[i] >= 0) perm[wbase + hist[bins[i]] + ranks[i]] = wbase + i * 256 + t;
}

// ---------------- gather-SpMM: one 8-lane group per ROW (no SpMM reduction) ----------------
// lane q of a group owns dims 8q..8q+7 (one uint4 of bf16 per edge). 8 rows/wave.
// Rows window-degree-sorted so the 8 lockstep groups finish together.
// x6 main loop (6 independent gathers in flight/lane, dup-free) + x2/x1 tail.
// Single-use streams (ccol, perm, rs) use NON-TEMPORAL loads so they don't evict
// the hot feature tables from L2 (features have ~17x reuse; streams have 1x).
// NO __launch_bounds__ (R1/R3: forced VGPR cap -> scratch spill -> +60MB r/w).
struct GA {
    const int* rs; const int* ccol; const float* isd;
    const unsigned* srcA; const unsigned* srcB; int na;
    const float* inA; const float* inB;
    unsigned* feat_out; float* dst0; void* dst1;
    const float* coefs; const float* modalp; int mi; int n;
};

#define EDGE_FMA(f, v)                                                        \
    a[0] = fmaf(v, blo(f.x), a[0]); a[1] = fmaf(v, bhi(f.x), a[1]);           \
    a[2] = fmaf(v, blo(f.y), a[2]); a[3] = fmaf(v, bhi(f.y), a[3]);           \
    a[4] = fmaf(v, blo(f.z), a[4]); a[5] = fmaf(v, bhi(f.z), a[5]);           \
    a[6] = fmaf(v, blo(f.w), a[6]); a[7] = fmaf(v, bhi(f.w), a[7]);

#define EDGE_ADD2(f0, f1)                                                     \
    a[0] += blo(f0.x) + blo(f1.x); a[1] += bhi(f0.x) + bhi(f1.x);             \
    a[2] += blo(f0.y) + blo(f1.y); a[3] += bhi(f0.y) + bhi(f1.y);             \
    a[4] += blo(f0.z) + blo(f1.z); a[5] += bhi(f0.z) + bhi(f1.z);             \
    a[6] += blo(f0.w) + blo(f1.w); a[7] += bhi(f0.w) + bhi(f1.w);

template <bool FIRST, bool A0, bool A1, bool BF16D1>
__global__ void spmm_norm_kernel(GA A, GA B, const int* __restrict__ perm, int ntot) {
    int lane = threadIdx.x & 63;
    int row = (blockIdx.x * (blockDim.x >> 6) + (threadIdx.x >> 6)) * 8 + (lane >> 3);
    if (row >= ntot) return;
    row = NTL(perm + row);
    GA G; int r;
    if (row < A.n) { G = A; r = row; }
    else           { G = B; r = row - A.n; if (r >= G.n) return; }
    int q = lane & 7;
    int s = NTL(G.rs + r), e = NTL(G.rs + r + 1);
    float isr = G.isd[r];
    const unsigned* src; int coff;
    if (FIRST && r < G.na) { src = G.srcB; coff = G.na; }
    else                   { src = G.srcA; coff = 0; }
    src += (q << 2);
    const int* cc = G.ccol;
    const float* isdp = G.isd;
    float a[8];
#pragma unroll
    for (int j = 0; j < 8; ++j) a[j] = 0.f;
    int k = s;
    for (; k + 5 < e; k += 6) {   // x6: six independent gathers in flight
        int c0 = NTL(cc + k), c1 = NTL(cc + k + 1), c2 = NTL(cc + k + 2);
        int c3 = NTL(cc + k + 3), c4 = NTL(cc + k + 4), c5 = NTL(cc + k + 5);
        uint4 f0 = *(const uint4*)(src + (size_t)(c0 - coff) * 32);
        uint4 f1 = *(const uint4*)(src + (size_t)(c1 - coff) * 32);
        uint4 f2 = *(const uint4*)(src + (size_t)(c2 - coff) * 32);
        uint4 f3 = *(const uint4*)(src + (size_t)(c3 - coff) * 32);
        uint4 f4 = *(const uint4*)(src + (size_t)(c4 - coff) * 32);
        uint4 f5 = *(const uint4*)(src + (size_t)(c5 - coff) * 32);
        if (FIRST) {
            float v0 = isdp[c0], v1 = isdp[c1], v2 = isdp[c2];
            float v3 = isdp[c3], v4 = isdp[c4], v5 = isdp[c5];
            EDGE_FMA(f0, v0) EDGE_FMA(f1, v1) EDGE_FMA(f2, v2)
            EDGE_FMA(f3, v3) EDGE_FMA(f4, v4) EDGE_FMA(f5, v5)
        } else {
            EDGE_ADD2(f0, f1) EDGE_ADD2(f2, f3) EDGE_ADD2(f4, f5)
        }
    }
    for (; k + 1 < e; k += 2) {
        int c0 = NTL(cc + k), c1 = NTL(cc + k + 1);
        uint4 f0 = *(const uint4*)(src + (size_t)(c0 - coff) * 32);
        uint4 f1 = *(const uint4*)(src + (size_t)(c1 - coff) * 32);
        if (FIRST) {
            float v0 = isdp[c0], v1 = isdp[c1];
            EDGE_FMA(f0, v0) EDGE_FMA(f1, v1)
        } else {
            EDGE_ADD2(f0, f1)
        }
    }
    if (k < e) {
        int c0 = NTL(cc + k);
        uint4 f0 = *(const uint4*)(src + (size_t)(c0 - coff) * 32);
        if (FIRST) {
            float v0 = isdp[c0];
            EDGE_FMA(f0, v0)
        } else {
            a[0] += blo(f0.x); a[1] += bhi(f0.x);
            a[2] += blo(f0.y); a[3] += bhi(f0.y);
            a[4] += blo(f0.z); a[5] += bhi(f0.z);
            a[6] += blo(f0.w); a[7] += bhi(f0.w);
        }
    }
    float s2 = 0.f;
#pragma unroll
    for (int j = 0; j < 8; ++j) s2 += a[j] * a[j];
    s2 += __shfl_xor(s2, 1, 64);
    s2 += __shfl_xor(s2, 2, 64);
    s2 += __shfl_xor(s2, 4, 64);
    float inv = 1.0f / fmaxf(sqrtf(s2), 1e-12f);   // scale-invariant: isr-free
    float mm = G.modalp[G.mi];
    size_t ro = (size_t)r * D + (q << 3);
    float ctb[8];
    if (FIRST) {
        float isr2 = isr * isr;                     // feat stored = isd_row * raw layer-1
        uint4 fw;
        fw.x = packbf(isr2 * a[0], isr2 * a[1]);
        fw.y = packbf(isr2 * a[2], isr2 * a[3]);
        fw.z = packbf(isr2 * a[4], isr2 * a[5]);
        fw.w = packbf(isr2 * a[6], isr2 * a[7]);
        *(uint4*)(G.feat_out + (size_t)r * 32 + (q << 2)) = fw;
        const float* ib = (r < G.na) ? (G.inA + ro) : (G.inB + (size_t)(r - G.na) * D + (q << 3));
        float4 a0 = *(const float4*)ib;
        float4 a1 = *(const float4*)(ib + 4);
        float c0 = G.coefs[0], c1m = G.coefs[1] * inv;
        ctb[0] = mm * fmaf(c0, a0.x, c1m * a[0]);
        ctb[1] = mm * fmaf(c0, a0.y, c1m * a[1]);
        ctb[2] = mm * fmaf(c0, a0.z, c1m * a[2]);
        ctb[3] = mm * fmaf(c0, a0.w, c1m * a[3]);
        ctb[4] = mm * fmaf(c0, a1.x, c1m * a[4]);
        ctb[5] = mm * fmaf(c0, a1.y, c1m * a[5]);
        ctb[6] = mm * fmaf(c0, a1.z, c1m * a[6]);
        ctb[7] = mm * fmaf(c0, a1.w, c1m * a[7]);
    } else {
        float mc = mm * G.coefs[2] * inv;
#pragma unroll
        for (int j = 0; j < 8; ++j) ctb[j] = mc * a[j];
    }
    if (r < G.na) {
        if (A0) {
            *(float4*)(G.dst0 + ro) = make_float4(ctb[0], ctb[1], ctb[2], ctb[3]);
            *(float4*)(G.dst0 + ro + 4) = make_float4(ctb[4], ctb[5], ctb[6], ctb[7]);
        } else {
            add4((float4*)(G.dst0 + ro), ctb[0], ctb[1], ctb[2], ctb[3]);
            add4((float4*)(G.dst0 + ro + 4), ctb[4], ctb[5], ctb[6], ctb[7]);
        }
    } else if (BF16D1) {
        unsigned* p = (unsigned*)G.dst1 + (size_t)(r - G.na) * 32 + (q << 2);
        if (!A1) {
            uint4 cur = *(const uint4*)p;
            ctb[0] += blo(cur.x); ctb[1] += bhi(cur.x);
            ctb[2] += blo(cur.y); ctb[3] += bhi(cur.y);
            ctb[4] += blo(cur.z); ctb[5] += bhi(cur.z);
            ctb[6] += blo(cur.w); ctb[7] += bhi(cur.w);
        }
        uint4 w;
        w.x = packbf(ctb[0], ctb[1]); w.y = packbf(ctb[2], ctb[3]);
        w.z = packbf(ctb[4], ctb[5]); w.w = packbf(ctb[6], ctb[7]);
        *(uint4*)p = w;
    } else {
        float* d1 = (float*)G.dst1 + (size_t)(r - G.na) * D + (q << 3);
        add4((float4*)d1, ctb[0], ctb[1], ctb[2], ctb[3]);
        add4((float4*)(d1 + 4), ctb[4], ctb[5], ctb[6], ctb[7]);
    }
}

// merged cross-aggs, 8-lane group per row — zero shuffles; window-degree-sorted rows; x6 loop
__global__ void agg2_kernel(const int* __restrict__ rsA, const int* __restrict__ ccA,
                            const unsigned* __restrict__ sA, float* __restrict__ oA,
                            int naA, int nA,
                            const int* __restrict__ rsB, const int* __restrict__ ccB,
                            const unsigned* __restrict__ sB, float* __restrict__ oB,
                            int naB, int nB, const int* __restrict__ perm) {
    int lane = threadIdx.x & 63;
    int row = (blockIdx.x * (blockDim.x >> 6) + (threadIdx.x >> 6)) * 8 + (lane >> 3);
    if (row >= nA + nB) return;
    row = NTL(perm + row);
    const int* rs; const int* cc; const unsigned* src; float* out; int na; int r;
    if (row < nA) { rs = rsA; cc = ccA; src = sA; out = oA; na = naA; r = row; }
    else          { rs = rsB; cc = ccB; src = sB; out = oB; na = naB; r = row - nA; }
    int q = lane & 7;
    src += (q << 2);
    int s = NTL(rs + r), e = NTL(rs + r + 1);
    float a[8];
#pragma unroll
    for (int j = 0; j < 8; ++j) a[j] = 0.f;
    int k = s;
    for (; k + 5 < e; k += 6) {
        int c0 = NTL(cc + k) - na, c1 = NTL(cc + k + 1) - na, c2 = NTL(cc + k + 2) - na;
        int c3 = NTL(cc + k + 3) - na, c4 = NTL(cc + k + 4) - na, c5 = NTL(cc + k + 5) - na;
        uint4 f0 = *(const uint4*)(src + (size_t)c0 * 32);
        uint4 f1 = *(const uint4*)(src + (size_t)c1 * 32);
        uint4 f2 = *(const uint4*)(src + (size_t)c2 * 32);
        uint4 f3 = *(const uint4*)(src + (size_t)c3 * 32);
        uint4 f4 = *(const uint4*)(src + (size_t)c4 * 32);
        uint4 f5 = *(const uint4*)(src + (size_t)c5 * 32);
        EDGE_ADD2(f0, f1) EDGE_ADD2(f2, f3) EDGE_ADD2(f4, f5)
    }
    for (; k + 1 < e; k += 2) {
        int c0 = NTL(cc + k) - na, c1 = NTL(cc + k + 1) - na;
        uint4 f0 = *(const uint4*)(src + (size_t)c0 * 32);
        uint4 f1 = *(const uint4*)(src + (size_t)c1 * 32);
        EDGE_ADD2(f0, f1)
    }
    if (k < e) {
        int c0 = NTL(cc + k) - na;
        uint4 f0 = *(const uint4*)(src + (size_t)c0 * 32);
        a[0] += blo(f0.x); a[1] += bhi(f0.x);
        a[2] += blo(f0.y); a[3] += bhi(f0.y);
        a[4] += blo(f0.z); a[5] += bhi(f0.z);
        a[6] += blo(f0.w); a[7] += bhi(f0.w);
    }
    float ad = 1.0f / ((float)(e - s) + 1e-8f);
    float* p = out + (size_t)r * D + (q << 3);
    add4((float4*)p, ad * a[0], ad * a[1], ad * a[2], ad * a[3]);
    add4((float4*)(p + 4), ad * a[4], ad * a[5], ad * a[6], ad * a[7]);
}

extern "C" void kernel_launch(void* const* d_in, const int* in_sizes, int n_in,
                              void* d_out, int out_size, void* d_ws, size_t ws_size,
                              hipStream_t stream) {
    const float* users   = (const float*)d_in[0];
    const float* bundles = (const float*)d_in[1];
    const float* items   = (const float*)d_in[2];
    const int*   ub_rows = (const int*)d_in[3];
    const int*   ub_cols = (const int*)d_in[4];
    const int*   ui_rows = (const int*)d_in[6];
    const int*   ui_cols = (const int*)d_in[7];
    const int*   bi_rows = (const int*)d_in[9];
    const int*   bi_cols = (const int*)d_in[10];
    const float* ub_coefs = (const float*)d_in[18];
    const float* ui_coefs = (const float*)d_in[19];
    const float* bi_coefs = (const float*)d_in[20];
    const float* modal    = (const float*)d_in[21];

    const int NU_ = in_sizes[0] / D;
    const int NB_ = in_sizes[1] / D;
    const int NI_ = in_sizes[2] / D;
    const int ne_ub = in_sizes[3];
    const int ne_ui = in_sizes[6];
    const int ne_bi = in_sizes[9];

    const int n_ui = NU_ + NI_;
    const int n_bi = NB_ + NI_;
    const int n_ub = NU_ + NB_;

    float* out = (float*)d_out;

    // ws layout (4B units), total 16,956,224 = 67.8 MB:
    int*      rs_ui  = (int*)d_ws;
    int*      rs_bi  = rs_ui + 90112;
    int*      rs_ub  = rs_bi + 70144;
    float*    isd_ui = (float*)(rs_ub + 40192);
    float*    isd_bi = isd_ui + 90112;
    float*    isd_ub = isd_bi + 70144;
    int*      hofs   = (int*)(isd_ub + 40192);
    int*      bsum   = hofs + 393280;
    int*      ccol   = bsum + 2048;
    int*      histG  = ccol;                       // aliases ccol (dead before sort writes)
    unsigned* SU     = (unsigned*)(ccol + 4000000);
    unsigned* SB     = SU + 960000;
    unsigned* SI     = SB + 320000;
    unsigned* ovl    = SI + 1920000;
    unsigned* ebuf   = ovl;
    unsigned* sfB_ui = ovl;
    unsigned* sfB_bi = sfB_ui + 2880000;
    unsigned* IT1b   = sfB_bi + 2240000;
    unsigned* IT2b   = IT1b + 1920000;
    unsigned* sfB_ub = IT1b;                       // aliases IT1b (dead after aggs)

    int* ccol_ui = ccol;
    int* ccol_bi = ccol + ne_ui;
    int* ccol_ub = ccol + ne_ui + ne_bi;

    // window-sorted perms live in dead hofs region (hofs dead after sort_bucket)
    const int n0 = n_ui + n_bi, n1 = n_ub, n2 = NU_ + NB_;
    int* perm0 = hofs;                 // size n0
    int* perm1 = perm0 + n0;           // size n1
    int* perm2 = perm1 + n1;           // size n2  (n0+n1+n2 <= 240,000 << 393,280)

    float* out_u = out;
    float* out_b = out + (size_t)NU_ * D;

    {
        int tot2 = (NU_ + NB_ + NI_) * 32;
        prep_kernel<<<768 + (tot2 + 255) / 256, 256, 0, stream>>>(
            users, bundles, items, SU, SB, SI, NU_ * 32, NB_ * 32, NI_ * 32,
            ui_rows, bi_rows, ub_rows, ne_ui, ne_bi, ne_ub, n_ui, n_bi, n_ub, histG);
    }
    scan1_kernel<<<1536, 256, 0, stream>>>(histG, hofs, bsum, 393216);
    scan2_kernel<<<1, 1024, 0, stream>>>(bsum, 1536);
    bucket_scatter_kernel<<<768, 256, 0, stream>>>(
        ui_rows, ui_cols, bi_rows, bi_cols, ub_rows, ub_cols,
        ne_ui, ne_bi, ne_ub, n_ui, n_bi, n_ub, hofs, bsum, ebuf);
    sort_bucket_kernel<<<1536, 256, 0, stream>>>(
        ebuf, hofs, bsum, rs_ui, rs_bi, rs_ub, isd_ui, isd_bi, isd_ub, ccol,
        ne_ui, ne_bi, ne_ub, n_ui, n_bi, n_ub);

    // window-local degree sort (rs arrays final; hofs/ebuf now dead)
    {
        int w0 = (n0 + WIN - 1) / WIN, w1 = (n1 + WIN - 1) / WIN, w2 = (n2 + WIN - 1) / WIN;
        winsort_kernel<<<w0 + w1 + w2, 256, 0, stream>>>(
            rs_ui, rs_bi, rs_ub, n_ui, NU_, n0, n1, n2, w0, w1, perm0, perm1, perm2);
    }

    GA gUI = { rs_ui, ccol_ui, isd_ui, SU, SI, NU_, users, items,
               sfB_ui, out_u, (void*)IT1b, ui_coefs, modal, 1, n_ui };
    GA gBI = { rs_bi, ccol_bi, isd_bi, SB, SI, NB_, bundles, items,
               sfB_bi, out_b, (void*)IT2b, bi_coefs, modal, 2, n_bi };
    GA gUB = { rs_ub, ccol_ub, isd_ub, SU, SB, NU_, users, bundles,
               sfB_ub, out_u, (void*)out_b, ub_coefs, modal, 0, n_ub };
    GA gUI2 = gUI; gUI2.srcA = sfB_ui;
    GA gBI2 = gBI; gBI2.srcA = sfB_bi;
    GA gUB2 = gUB; gUB2.srcA = sfB_ub;

    int ntotL = n_ui + n_bi;
    // 32 rows per block (4 waves x 8 rows)
    spmm_norm_kernel<true,  true,  true,  true ><<<(ntotL + 31) / 32, 256, 0, stream>>>(gUI,  gBI,  perm0, ntotL);
    spmm_norm_kernel<false, false, false, true ><<<(ntotL + 31) / 32, 256, 0, stream>>>(gUI2, gBI2, perm0, ntotL);

    agg2_kernel<<<(NU_ + NB_ + 31) / 32, 256, 0, stream>>>(
        rs_ui, ccol_ui, IT2b, out_u, NU_, NU_,
        rs_bi, ccol_bi, IT1b, out_b, NB_, NB_, perm2);

    spmm_norm_kernel<true,  false, false, false><<<(n_ub + 31) / 32, 256, 0, stream>>>(gUB,  gUB,  perm1, n_ub);
    spmm_norm_kernel<false, false, false, false><<<(n_ub + 31) / 32, 256, 0, stream>>>(gUB2, gUB2, perm1, n_ub);
}

// Round 8
// 453.038 us; speedup vs baseline: 1.1475x; 1.1475x over previous
//
#include <hip/hip_runtime.h>

#define D 64
#define WIN 2048
// NT-load experiment (R7) REVERTED: ccol/perm lines are touched ~16x (sequential
// int stream, 64B line = 16 entries); `nt` evicts after first touch -> +15MB FETCH,
// rate 2.8->2.2 TB/s. Plain loads restore L1/L2 residency of the index stream.
#define NTL(p) (*(p))

// ---------------- bf16 helpers ----------------
__device__ __forceinline__ float blo(unsigned u) { return __uint_as_float(u << 16); }
__device__ __forceinline__ float bhi(unsigned u) { return __uint_as_float(u & 0xffff0000u); }
__device__ __forceinline__ unsigned rne(float f) {
    unsigned u = __float_as_uint(f);
    return (u + 0x7fffu + ((u >> 16) & 1u)) >> 16;
}
__device__ __forceinline__ unsigned packbf(float a, float b) {
    unsigned ub = __float_as_uint(b);
    return rne(a) | ((ub + 0x7fffu + ((ub >> 16) & 1u)) & 0xffff0000u);
}
__device__ __forceinline__ void add4(float4* p, float a, float b, float c, float d) {
    float4 o = *p; o.x += a; o.y += b; o.z += c; o.w += d; *p = o;
}

// ---------------- fused bf16-convert + 3-graph bucket histogram ----------------
// blocks [0,768): histogram (3 graphs x 256 chunks); blocks >=768: bf16 conversion.
__global__ void prep_kernel(const float* __restrict__ u, const float* __restrict__ b,
                            const float* __restrict__ it,
                            unsigned* __restrict__ SU, unsigned* __restrict__ SB,
                            unsigned* __restrict__ SI, int nU2, int nB2, int nI2,
                            const int* __restrict__ r0, const int* __restrict__ r1,
                            const int* __restrict__ r2,
                            int ne0, int ne1, int ne2, int n0, int n1, int n2,
                            int* __restrict__ histG) {
    __shared__ int h[512];
    int t = threadIdx.x;
    if (blockIdx.x < 768) {
        int g = blockIdx.x >> 8, blk = blockIdx.x & 255;
        const int* rows = (g == 0) ? r0 : (g == 1) ? r1 : r2;
        int ne = (g == 0) ? ne0 : (g == 1) ? ne1 : ne2;
        unsigned n = (unsigned)((g == 0) ? n0 : (g == 1) ? n1 : n2);
        h[t] = 0; h[t + 256] = 0;
        __syncthreads();
        int C = (ne + 255) >> 8;
        int e0 = blk * C, e1 = min(ne, e0 + C);
        for (int e = e0 + t; e < e1; e += 256) {
            unsigned bb = ((unsigned)rows[e] << 9) / n;
            atomicAdd(&h[bb], 1);
        }
        __syncthreads();
        histG[(((g << 9) | t) << 8) | blk] = h[t];
        histG[(((g << 9) | (t + 256)) << 8) | blk] = h[t + 256];
    } else {
        int i = (blockIdx.x - 768) * 256 + t;
        if (i < nU2) {
            float2 f = ((const float2*)u)[i];
            SU[i] = packbf(f.x, f.y);
        } else if (i < nU2 + nB2) {
            int j = i - nU2;
            float2 f = ((const float2*)b)[j];
            SB[j] = packbf(f.x, f.y);
        } else if (i < nU2 + nB2 + nI2) {
            int j = i - nU2 - nB2;
            float2 f = ((const float2*)it)[j];
            SI[j] = packbf(f.x, f.y);
        }
    }
}

__global__ void scan1_kernel(const int* __restrict__ deg, int* __restrict__ rs,
                             int* __restrict__ bsum, int n) {
    __shared__ int tmp[256];
    int t = threadIdx.x;
    int g = blockIdx.x * 256 + t;
    int v = (g < n) ? deg[g] : 0;
    tmp[t] = v;
    __syncthreads();
    for (int off = 1; off < 256; off <<= 1) {
        int x = (t >= off) ? tmp[t - off] : 0;
        __syncthreads();
        tmp[t] += x;
        __syncthreads();
    }
    if (g < n) rs[g] = tmp[t] - v;
    if (t == 255) bsum[blockIdx.x] = tmp[255];
}

__global__ void scan2_kernel(int* __restrict__ bsum, int B) {
    __shared__ int tmp[2048];
    int t = threadIdx.x;
    int v0 = (t < B) ? bsum[t] : 0;
    int v1 = (t + 1024 < B) ? bsum[t + 1024] : 0;
    tmp[t] = v0; tmp[t + 1024] = v1;
    __syncthreads();
    for (int off = 1; off < 2048; off <<= 1) {
        int a0 = (t >= off) ? tmp[t - off] : 0;
        int a1 = ((t + 1024) >= off) ? tmp[t + 1024 - off] : 0;
        __syncthreads();
        tmp[t] += a0; tmp[t + 1024] += a1;
        __syncthreads();
    }
    if (t < B) bsum[t] = tmp[t] - v0;
    if (t + 1024 < B) bsum[t + 1024] = tmp[t + 1024] - v1;
}

// scan3 folded into the two consumers below: hofs[i] is exclusive-within-block,
// bsum[i>>8] is the block offset -> absolute = hofs[i] + bsum[i>>8].

// LDS-staged: local hist -> local scan -> scatter into LDS -> per-bucket coalesced copy out.
__global__ void bucket_scatter_kernel(const int* __restrict__ r0, const int* __restrict__ c0,
                                      const int* __restrict__ r1, const int* __restrict__ c1,
                                      const int* __restrict__ r2, const int* __restrict__ c2,
                                      int ne0, int ne1, int ne2, int n0, int n1, int n2,
                                      const int* __restrict__ hofs, const int* __restrict__ bsum,
                                      unsigned* __restrict__ ebuf) {
    __shared__ unsigned se[8192];    // staged packed edges (chunk <= 6250)
    __shared__ int h[512];
    __shared__ int lofs[512];
    __shared__ int cur[512];
    __shared__ int gb[512];
    __shared__ int tmp[512];
    int t = threadIdx.x;
    int g = blockIdx.x >> 8, blk = blockIdx.x & 255;
    const int* rows = (g == 0) ? r0 : (g == 1) ? r1 : r2;
    const int* cols = (g == 0) ? c0 : (g == 1) ? c1 : c2;
    int ne = (g == 0) ? ne0 : (g == 1) ? ne1 : ne2;
    int n  = (g == 0) ? n0  : (g == 1) ? n1  : n2;
    h[t] = 0; h[t + 256] = 0;
    __syncthreads();
    int C = (ne + 255) >> 8;
    int e0 = blk * C, e1 = min(ne, e0 + C);
    for (int e = e0 + t; e < e1; e += 256) {
        unsigned b = ((unsigned)rows[e] << 9) / (unsigned)n;
        atomicAdd(&h[b], 1);
    }
    __syncthreads();
    tmp[t] = h[t]; tmp[t + 256] = h[t + 256];
    __syncthreads();
    for (int off = 1; off < 512; off <<= 1) {
        int a0 = (t >= off) ? tmp[t - off] : 0;
        int a1 = ((t + 256) >= off) ? tmp[t + 256 - off] : 0;
        __syncthreads();
        tmp[t] += a0; tmp[t + 256] += a1;
        __syncthreads();
    }
    lofs[t] = tmp[t] - h[t]; lofs[t + 256] = tmp[t + 256] - h[t + 256];
    cur[t] = lofs[t]; cur[t + 256] = lofs[t + 256];
    gb[t] = hofs[(((g << 9) | t) << 8) | blk] + bsum[(g << 9) | t];
    gb[t + 256] = hofs[(((g << 9) | (t + 256)) << 8) | blk] + bsum[(g << 9) | (t + 256)];
    __syncthreads();
    for (int e = e0 + t; e < e1; e += 256) {
        int r = rows[e];
        unsigned b = ((unsigned)r << 9) / (unsigned)n;
        int rb0v = ((int)b * n + 511) >> 9;
        int p = atomicAdd(&cur[b], 1);
        se[p] = ((unsigned)(r - rb0v) << 23) | (unsigned)cols[e];
    }
    __syncthreads();
    int wid = t >> 6, lane = t & 63;
    for (int b = wid; b < 512; b += 4) {
        int lb = lofs[b], len = cur[b] - lb, gbb = gb[b];
        for (int j = lane; j < len; j += 64) ebuf[gbb + j] = se[lb + j];
    }
}

// LDS-staged: scatter columns into LDS by row-cursor, then sequential ccol write.
__global__ void sort_bucket_kernel(const unsigned* __restrict__ ebuf, const int* __restrict__ hofs,
                                   const int* __restrict__ bsum,
                                   int* __restrict__ rs0, int* __restrict__ rs1, int* __restrict__ rs2,
                                   float* __restrict__ isd0, float* __restrict__ isd1,
                                   float* __restrict__ isd2, int* __restrict__ ccol,
                                   int ne0, int ne1, int ne2, int n0, int n1, int n2) {
    __shared__ int cnt[256];
    __shared__ int pfx[256];
    __shared__ int scol[8192];
    int t = threadIdx.x;
    int g = blockIdx.x >> 9, b = blockIdx.x & 511;
    int ne = (g == 0) ? ne0 : (g == 1) ? ne1 : ne2;
    int n  = (g == 0) ? n0  : (g == 1) ? n1  : n2;
    int O  = (g == 0) ? 0   : (g == 1) ? ne0 : ne0 + ne1;
    int*   rs  = (g == 0) ? rs0  : (g == 1) ? rs1  : rs2;
    float* isd = (g == 0) ? isd0 : (g == 1) ? isd1 : isd2;
    int rb0 = (b * n + 511) >> 9;
    int rb1 = ((b + 1) * n + 511) >> 9;
    int R = rb1 - rb0;
    cnt[t] = 0;
    __syncthreads();
    int base = hofs[((g << 9) | b) << 8] + bsum[(g << 9) | b];
    int end  = (b == 511) ? (O + ne)
                          : hofs[((g << 9) | (b + 1)) << 8] + bsum[(g << 9) | (b + 1)];
    int E = end - base;
    for (int e = base + t; e < end; e += 256)
        atomicAdd(&cnt[ebuf[e] >> 23], 1);
    __syncthreads();
    pfx[t] = cnt[t];
    __syncthreads();
    for (int off = 1; off < 256; off <<= 1) {
        int v = (t >= off) ? pfx[t - off] : 0;
        __syncthreads();
        pfx[t] += v;
        __syncthreads();
    }
    int c0 = cnt[t], ex = pfx[t] - c0;
    if (t < R) {
        rs[rb0 + t] = base + ex - O;
        isd[rb0 + t] = 1.0f / (sqrtf((float)c0) + 1e-8f);
    }
    __syncthreads();
    bool fits = (E <= 8192);
    cnt[t] = fits ? ex : (base + ex);
    __syncthreads();
    for (int e = base + t; e < end; e += 256) {
        unsigned p = ebuf[e];
        int pos = atomicAdd(&cnt[p >> 23], 1);
        if (fits) scol[pos] = (int)(p & 0x7fffffu);
        else      ccol[pos] = (int)(p & 0x7fffffu);
    }
    if (fits) {
        __syncthreads();
        for (int j = t; j < E; j += 256) ccol[base + j] = scol[j];
    }
    if (b == 511 && t == 0) rs[n] = ne;
}

// ---------------- window-local degree sort (WIN=2048, one block/window) ----------------
__device__ __forceinline__ int row_deg(int list, int r, const int* rs_ui, const int* rs_bi,
                                       const int* rs_ub, int n_ui, int NU) {
    const int* rs; int rr;
    if (list == 0) { if (r < n_ui) { rs = rs_ui; rr = r; } else { rs = rs_bi; rr = r - n_ui; } }
    else if (list == 1) { rs = rs_ub; rr = r; }
    else { if (r < NU) { rs = rs_ui; rr = r; } else { rs = rs_bi; rr = r - NU; } }
    return rs[rr + 1] - rs[rr];
}

__global__ void winsort_kernel(const int* __restrict__ rs_ui, const int* __restrict__ rs_bi,
                               const int* __restrict__ rs_ub,
                               int n_ui, int NU, int n0, int n1, int n2,
                               int w0, int w1,
                               int* __restrict__ perm0, int* __restrict__ perm1,
                               int* __restrict__ perm2) {
    __shared__ int hist[256];
    __shared__ int pfx[256];
    int t = threadIdx.x;
    int blk = blockIdx.x, list, wbase, n; int* perm;
    if (blk < w0)           { list = 0; wbase = blk * WIN;             n = n0; perm = perm0; }
    else if (blk < w0 + w1) { list = 1; wbase = (blk - w0) * WIN;      n = n1; perm = perm1; }
    else                    { list = 2; wbase = (blk - w0 - w1) * WIN; n = n2; perm = perm2; }
    hist[t] = 0;
    __syncthreads();
    int lim = min(n - wbase, WIN);
    int bins[8], ranks[8];
#pragma unroll
    for (int i = 0; i < 8; ++i) {
        int rr = i * 256 + t;
        if (rr < lim) {
            int d = row_deg(list, wbase + rr, rs_ui, rs_bi, rs_ub, n_ui, NU);
            int b = 255 - min(d, 255);          // descending: long rows first
            bins[i] = b;
            ranks[i] = atomicAdd(&hist[b], 1);
        } else bins[i] = -1;
    }
    __syncthreads();
    int h = hist[t];
    pfx[t] = h;
    __syncthreads();
    for (int off = 1; off < 256; off <<= 1) {
        int x = (t >= off) ? pfx[t - off] : 0;
        __syncthreads();
        pfx[t] += x;
        __syncthreads();
    }
    hist[t] = pfx[t] - h;                        // exclusive base per bin
    __syncthreads();
#pragma unroll
    for (int i = 0; i < 8; ++i)
        if (bins[i] >= 0) perm[wbase + hist[bins[i]] + ranks[i]] = wbase + i * 256 + t;
}

// ---------------- gather-SpMM: one 8-lane group per ROW (no SpMM reduction) ----------------
// lane q of a group owns dims 8q..8q+7 (one uint4 of bf16 per edge). 8 rows/wave.
// Rows window-degree-sorted so the 8 lockstep groups finish together.
// x6 main loop (6 independent gathers in flight/lane, dup-free) + x2/x1 tail.
// NO __launch_bounds__ (R1/R3: forced VGPR cap -> scratch spill -> +60MB r/w).
struct GA {
    const int* rs; const int* ccol; const float* isd;
    const unsigned* srcA; const unsigned* srcB; int na;
    const float* inA; const float* inB;
    unsigned* feat_out; float* dst0; void* dst1;
    const float* coefs; const float* modalp; int mi; int n;
};

#define EDGE_FMA(f, v)                                                        \
    a[0] = fmaf(v, blo(f.x), a[0]); a[1] = fmaf(v, bhi(f.x), a[1]);           \
    a[2] = fmaf(v, blo(f.y), a[2]); a[3] = fmaf(v, bhi(f.y), a[3]);           \
    a[4] = fmaf(v, blo(f.z), a[4]); a[5] = fmaf(v, bhi(f.z), a[5]);           \
    a[6] = fmaf(v, blo(f.w), a[6]); a[7] = fmaf(v, bhi(f.w), a[7]);

#define EDGE_ADD2(f0, f1)                                                     \
    a[0] += blo(f0.x) + blo(f1.x); a[1] += bhi(f0.x) + bhi(f1.x);             \
    a[2] += blo(f0.y) + blo(f1.y); a[3] += bhi(f0.y) + bhi(f1.y);             \
    a[4] += blo(f0.z) + blo(f1.z); a[5] += bhi(f0.z) + bhi(f1.z);             \
    a[6] += blo(f0.w) + blo(f1.w); a[7] += bhi(f0.w) + bhi(f1.w);

template <bool FIRST, bool A0, bool A1, bool BF16D1>
__global__ void spmm_norm_kernel(GA A, GA B, const int* __restrict__ perm, int ntot) {
    int lane = threadIdx.x & 63;
    int row = (blockIdx.x * (blockDim.x >> 6) + (threadIdx.x >> 6)) * 8 + (lane >> 3);
    if (row >= ntot) return;
    row = NTL(perm + row);
    GA G; int r;
    if (row < A.n) { G = A; r = row; }
    else           { G = B; r = row - A.n; if (r >= G.n) return; }
    int q = lane & 7;
    int s = NTL(G.rs + r), e = NTL(G.rs + r + 1);
    float isr = G.isd[r];
    const unsigned* src; int coff;
    if (FIRST && r < G.na) { src = G.srcB; coff = G.na; }
    else                   { src = G.srcA; coff = 0; }
    src += (q << 2);
    const int* cc = G.ccol;
    const float* isdp = G.isd;
    float a[8];
#pragma unroll
    for (int j = 0; j < 8; ++j) a[j] = 0.f;
    int k = s;
    for (; k + 5 < e; k += 6) {   // x6: six independent gathers in flight
        int c0 = NTL(cc + k), c1 = NTL(cc + k + 1), c2 = NTL(cc + k + 2);
        int c3 = NTL(cc + k + 3), c4 = NTL(cc + k + 4), c5 = NTL(cc + k + 5);
        uint4 f0 = *(const uint4*)(src + (size_t)(c0 - coff) * 32);
        uint4 f1 = *(const uint4*)(src + (size_t)(c1 - coff) * 32);
        uint4 f2 = *(const uint4*)(src + (size_t)(c2 - coff) * 32);
        uint4 f3 = *(const uint4*)(src + (size_t)(c3 - coff) * 32);
        uint4 f4 = *(const uint4*)(src + (size_t)(c4 - coff) * 32);
        uint4 f5 = *(const uint4*)(src + (size_t)(c5 - coff) * 32);
        if (FIRST) {
            float v0 = isdp[c0], v1 = isdp[c1], v2 = isdp[c2];
            float v3 = isdp[c3], v4 = isdp[c4], v5 = isdp[c5];
            EDGE_FMA(f0, v0) EDGE_FMA(f1, v1) EDGE_FMA(f2, v2)
            EDGE_FMA(f3, v3) EDGE_FMA(f4, v4) EDGE_FMA(f5, v5)
        } else {
            EDGE_ADD2(f0, f1) EDGE_ADD2(f2, f3) EDGE_ADD2(f4, f5)
        }
    }
    for (; k + 1 < e; k += 2) {
        int c0 = NTL(cc + k), c1 = NTL(cc + k + 1);
        uint4 f0 = *(const uint4*)(src + (size_t)(c0 - coff) * 32);
        uint4 f1 = *(const uint4*)(src + (size_t)(c1 - coff) * 32);
        if (FIRST) {
            float v0 = isdp[c0], v1 = isdp[c1];
            EDGE_FMA(f0, v0) EDGE_FMA(f1, v1)
        } else {
            EDGE_ADD2(f0, f1)
        }
    }
    if (k < e) {
        int c0 = NTL(cc + k);
        uint4 f0 = *(const uint4*)(src + (size_t)(c0 - coff) * 32);
        if (FIRST) {
            float v0 = isdp[c0];
            EDGE_FMA(f0, v0)
        } else {
            a[0] += blo(f0.x); a[1] += bhi(f0.x);
            a[2] += blo(f0.y); a[3] += bhi(f0.y);
            a[4] += blo(f0.z); a[5] += bhi(f0.z);
            a[6] += blo(f0.w); a[7] += bhi(f0.w);
        }
    }
    float s2 = 0.f;
#pragma unroll
    for (int j = 0; j < 8; ++j) s2 += a[j] * a[j];
    s2 += __shfl_xor(s2, 1, 64);
    s2 += __shfl_xor(s2, 2, 64);
    s2 += __shfl_xor(s2, 4, 64);
    float inv = 1.0f / fmaxf(sqrtf(s2), 1e-12f);   // scale-invariant: isr-free
    float mm = G.modalp[G.mi];
    size_t ro = (size_t)r * D + (q << 3);
    float ctb[8];
    if (FIRST) {
        float isr2 = isr * isr;                     // feat stored = isd_row * raw layer-1
        uint4 fw;
        fw.x = packbf(isr2 * a[0], isr2 * a[1]);
        fw.y = packbf(isr2 * a[2], isr2 * a[3]);
        fw.z = packbf(isr2 * a[4], isr2 * a[5]);
        fw.w = packbf(isr2 * a[6], isr2 * a[7]);
        *(uint4*)(G.feat_out + (size_t)r * 32 + (q << 2)) = fw;
        const float* ib = (r < G.na) ? (G.inA + ro) : (G.inB + (size_t)(r - G.na) * D + (q << 3));
        float4 a0 = *(const float4*)ib;
        float4 a1 = *(const float4*)(ib + 4);
        float c0 = G.coefs[0], c1m = G.coefs[1] * inv;
        ctb[0] = mm * fmaf(c0, a0.x, c1m * a[0]);
        ctb[1] = mm * fmaf(c0, a0.y, c1m * a[1]);
        ctb[2] = mm * fmaf(c0, a0.z, c1m * a[2]);
        ctb[3] = mm * fmaf(c0, a0.w, c1m * a[3]);
        ctb[4] = mm * fmaf(c0, a1.x, c1m * a[4]);
        ctb[5] = mm * fmaf(c0, a1.y, c1m * a[5]);
        ctb[6] = mm * fmaf(c0, a1.z, c1m * a[6]);
        ctb[7] = mm * fmaf(c0, a1.w, c1m * a[7]);
    } else {
        float mc = mm * G.coefs[2] * inv;
#pragma unroll
        for (int j = 0; j < 8; ++j) ctb[j] = mc * a[j];
    }
    if (r < G.na) {
        if (A0) {
            *(float4*)(G.dst0 + ro) = make_float4(ctb[0], ctb[1], ctb[2], ctb[3]);
            *(float4*)(G.dst0 + ro + 4) = make_float4(ctb[4], ctb[5], ctb[6], ctb[7]);
        } else {
            add4((float4*)(G.dst0 + ro), ctb[0], ctb[1], ctb[2], ctb[3]);
            add4((float4*)(G.dst0 + ro + 4), ctb[4], ctb[5], ctb[6], ctb[7]);
        }
    } else if (BF16D1) {
        unsigned* p = (unsigned*)G.dst1 + (size_t)(r - G.na) * 32 + (q << 2);
        if (!A1) {
            uint4 cur = *(const uint4*)p;
            ctb[0] += blo(cur.x); ctb[1] += bhi(cur.x);
            ctb[2] += blo(cur.y); ctb[3] += bhi(cur.y);
            ctb[4] += blo(cur.z); ctb[5] += bhi(cur.z);
            ctb[6] += blo(cur.w); ctb[7] += bhi(cur.w);
        }
        uint4 w;
        w.x = packbf(ctb[0], ctb[1]); w.y = packbf(ctb[2], ctb[3]);
        w.z = packbf(ctb[4], ctb[5]); w.w = packbf(ctb[6], ctb[7]);
        *(uint4*)p = w;
    } else {
        float* d1 = (float*)G.dst1 + (size_t)(r - G.na) * D + (q << 3);
        add4((float4*)d1, ctb[0], ctb[1], ctb[2], ctb[3]);
        add4((float4*)(d1 + 4), ctb[4], ctb[5], ctb[6], ctb[7]);
    }
}

// merged cross-aggs, 8-lane group per row — zero shuffles; window-degree-sorted rows; x6 loop
__global__ void agg2_kernel(const int* __restrict__ rsA, const int* __restrict__ ccA,
                            const unsigned* __restrict__ sA, float* __restrict__ oA,
                            int naA, int nA,
                            const int* __restrict__ rsB, const int* __restrict__ ccB,
                            const unsigned* __restrict__ sB, float* __restrict__ oB,
                            int naB, int nB, const int* __restrict__ perm) {
    int lane = threadIdx.x & 63;
    int row = (blockIdx.x * (blockDim.x >> 6) + (threadIdx.x >> 6)) * 8 + (lane >> 3);
    if (row >= nA + nB) return;
    row = NTL(perm + row);
    const int* rs; const int* cc; const unsigned* src; float* out; int na; int r;
    if (row < nA) { rs = rsA; cc = ccA; src = sA; out = oA; na = naA; r = row; }
    else          { rs = rsB; cc = ccB; src = sB; out = oB; na = naB; r = row - nA; }
    int q = lane & 7;
    src += (q << 2);
    int s = NTL(rs + r), e = NTL(rs + r + 1);
    float a[8];
#pragma unroll
    for (int j = 0; j < 8; ++j) a[j] = 0.f;
    int k = s;
    for (; k + 5 < e; k += 6) {
        int c0 = NTL(cc + k) - na, c1 = NTL(cc + k + 1) - na, c2 = NTL(cc + k + 2) - na;
        int c3 = NTL(cc + k + 3) - na, c4 = NTL(cc + k + 4) - na, c5 = NTL(cc + k + 5) - na;
        uint4 f0 = *(const uint4*)(src + (size_t)c0 * 32);
        uint4 f1 = *(const uint4*)(src + (size_t)c1 * 32);
        uint4 f2 = *(const uint4*)(src + (size_t)c2 * 32);
        uint4 f3 = *(const uint4*)(src + (size_t)c3 * 32);
        uint4 f4 = *(const uint4*)(src + (size_t)c4 * 32);
        uint4 f5 = *(const uint4*)(src + (size_t)c5 * 32);
        EDGE_ADD2(f0, f1) EDGE_ADD2(f2, f3) EDGE_ADD2(f4, f5)
    }
    for (; k + 1 < e; k += 2) {
        int c0 = NTL(cc + k) - na, c1 = NTL(cc + k + 1) - na;
        uint4 f0 = *(const uint4*)(src + (size_t)c0 * 32);
        uint4 f1 = *(const uint4*)(src + (size_t)c1 * 32);
        EDGE_ADD2(f0, f1)
    }
    if (k < e) {
        int c0 = NTL(cc + k) - na;
        uint4 f0 = *(const uint4*)(src + (size_t)c0 * 32);
        a[0] += blo(f0.x); a[1] += bhi(f0.x);
        a[2] += blo(f0.y); a[3] += bhi(f0.y);
        a[4] += blo(f0.z); a[5] += bhi(f0.z);
        a[6] += blo(f0.w); a[7] += bhi(f0.w);
    }
    float ad = 1.0f / ((float)(e - s) + 1e-8f);
    float* p = out + (size_t)r * D + (q << 3);
    add4((float4*)p, ad * a[0], ad * a[1], ad * a[2], ad * a[3]);
    add4((float4*)(p + 4), ad * a[4], ad * a[5], ad * a[6], ad * a[7]);
}

extern "C" void kernel_launch(void* const* d_in, const int* in_sizes, int n_in,
                              void* d_out, int out_size, void* d_ws, size_t ws_size,
                              hipStream_t stream) {
    const float* users   = (const float*)d_in[0];
    const float* bundles = (const float*)d_in[1];
    const float* items   = (const float*)d_in[2];
    const int*   ub_rows = (const int*)d_in[3];
    const int*   ub_cols = (const int*)d_in[4];
    const int*   ui_rows = (const int*)d_in[6];
    const int*   ui_cols = (const int*)d_in[7];
    const int*   bi_rows = (const int*)d_in[9];
    const int*   bi_cols = (const int*)d_in[10];
    const float* ub_coefs = (const float*)d_in[18];
    const float* ui_coefs = (const float*)d_in[19];
    const float* bi_coefs = (const float*)d_in[20];
    const float* modal    = (const float*)d_in[21];

    const int NU_ = in_sizes[0] / D;
    const int NB_ = in_sizes[1] / D;
    const int NI_ = in_sizes[2] / D;
    const int ne_ub = in_sizes[3];
    const int ne_ui = in_sizes[6];
    const int ne_bi = in_sizes[9];

    const int n_ui = NU_ + NI_;
    const int n_bi = NB_ + NI_;
    const int n_ub = NU_ + NB_;

    float* out = (float*)d_out;

    // ws layout (4B units), total 16,956,224 = 67.8 MB:
    int*      rs_ui  = (int*)d_ws;
    int*      rs_bi  = rs_ui + 90112;
    int*      rs_ub  = rs_bi + 70144;
    float*    isd_ui = (float*)(rs_ub + 40192);
    float*    isd_bi = isd_ui + 90112;
    float*    isd_ub = isd_bi + 70144;
    int*      hofs   = (int*)(isd_ub + 40192);
    int*      bsum   = hofs + 393280;
    int*      ccol   = bsum + 2048;
    int*      histG  = ccol;                       // aliases ccol (dead before sort writes)
    unsigned* SU     = (unsigned*)(ccol + 4000000);
    unsigned* SB     = SU + 960000;
    unsigned* SI     = SB + 320000;
    unsigned* ovl    = SI + 1920000;
    unsigned* ebuf   = ovl;
    unsigned* sfB_ui = ovl;
    unsigned* sfB_bi = sfB_ui + 2880000;
    unsigned* IT1b   = sfB_bi + 2240000;
    unsigned* IT2b   = IT1b + 1920000;
    unsigned* sfB_ub = IT1b;                       // aliases IT1b (dead after aggs)

    int* ccol_ui = ccol;
    int* ccol_bi = ccol + ne_ui;
    int* ccol_ub = ccol + ne_ui + ne_bi;

    // window-sorted perms live in dead hofs region (hofs dead after sort_bucket)
    const int n0 = n_ui + n_bi, n1 = n_ub, n2 = NU_ + NB_;
    int* perm0 = hofs;                 // size n0
    int* perm1 = perm0 + n0;           // size n1
    int* perm2 = perm1 + n1;           // size n2  (n0+n1+n2 <= 240,000 << 393,280)

    float* out_u = out;
    float* out_b = out + (size_t)NU_ * D;

    {
        int tot2 = (NU_ + NB_ + NI_) * 32;
        prep_kernel<<<768 + (tot2 + 255) / 256, 256, 0, stream>>>(
            users, bundles, items, SU, SB, SI, NU_ * 32, NB_ * 32, NI_ * 32,
            ui_rows, bi_rows, ub_rows, ne_ui, ne_bi, ne_ub, n_ui, n_bi, n_ub, histG);
    }
    scan1_kernel<<<1536, 256, 0, stream>>>(histG, hofs, bsum, 393216);
    scan2_kernel<<<1, 1024, 0, stream>>>(bsum, 1536);
    bucket_scatter_kernel<<<768, 256, 0, stream>>>(
        ui_rows, ui_cols, bi_rows, bi_cols, ub_rows, ub_cols,
        ne_ui, ne_bi, ne_ub, n_ui, n_bi, n_ub, hofs, bsum, ebuf);
    sort_bucket_kernel<<<1536, 256, 0, stream>>>(
        ebuf, hofs, bsum, rs_ui, rs_bi, rs_ub, isd_ui, isd_bi, isd_ub, ccol,
        ne_ui, ne_bi, ne_ub, n_ui, n_bi, n_ub);

    // window-local degree sort (rs arrays final; hofs/ebuf now dead)
    {
        int w0 = (n0 + WIN - 1) / WIN, w1 = (n1 + WIN - 1) / WIN, w2 = (n2 + WIN - 1) / WIN;
        winsort_kernel<<<w0 + w1 + w2, 256, 0, stream>>>(
            rs_ui, rs_bi, rs_ub, n_ui, NU_, n0, n1, n2, w0, w1, perm0, perm1, perm2);
    }

    GA gUI = { rs_ui, ccol_ui, isd_ui, SU, SI, NU_, users, items,
               sfB_ui, out_u, (void*)IT1b, ui_coefs, modal, 1, n_ui };
    GA gBI = { rs_bi, ccol_bi, isd_bi, SB, SI, NB_, bundles, items,
               sfB_bi, out_b, (void*)IT2b, bi_coefs, modal, 2, n_bi };
    GA gUB = { rs_ub, ccol_ub, isd_ub, SU, SB, NU_, users, bundles,
               sfB_ub, out_u, (void*)out_b, ub_coefs, modal, 0, n_ub };
    GA gUI2 = gUI; gUI2.srcA = sfB_ui;
    GA gBI2 = gBI; gBI2.srcA = sfB_bi;
    GA gUB2 = gUB; gUB2.srcA = sfB_ub;

    int ntotL = n_ui + n_bi;
    // 32 rows per block (4 waves x 8 rows)
    spmm_norm_kernel<true,  true,  true,  true ><<<(ntotL + 31) / 32, 256, 0, stream>>>(gUI,  gBI,  perm0, ntotL);
    spmm_norm_kernel<false, false, false, true ><<<(ntotL + 31) / 32, 256, 0, stream>>>(gUI2, gBI2, perm0, ntotL);

    agg2_kernel<<<(NU_ + NB_ + 31) / 32, 256, 0, stream>>>(
        rs_ui, ccol_ui, IT2b, out_u, NU_, NU_,
        rs_bi, ccol_bi, IT1b, out_b, NB_, NB_, perm2);

    spmm_norm_kernel<true,  false, false, false><<<(n_ub + 31) / 32, 256, 0, stream>>>(gUB,  gUB,  perm1, n_ub);
    spmm_norm_kernel<false, false, false, false><<<(n_ub + 31) / 32, 256, 0, stream>>>(gUB2, gUB2, perm1, n_ub);
}